// Round 3
// baseline (319.603 us; speedup 1.0000x reference)
//
#include <hip/hip_runtime.h>

// SobelLoss: loss = valid * (|Sx (x) d| + |Sy (x) d|), d = pred - tgt.
// (B*T=12 images, H=512, W=512, F=8 fp32 channels, F innermost)
// valid = AND of mask over 3x3 (zero padded -> borders always 0).
//
// R3: separable sliding-window stencil.
//   v1 = d[h-1]+2d[h]+d[h+1], v2 = d[h+1]-d[h-1]  (registers, per column)
//   gx = v1[w+1]-v1[w-1],  gy = v2[w-1]+2v2[w]+v2[w+1]  (via LDS row exchange)
// Thread t owns staged px t>>1 (q = t&1), outputs px (t>>1)+1; its own v is
// the left neighbor, so only 3 b128 + 2 b32 LDS reads per output.
// R2 was LDS-latency bound: 36 b128 + 36 b32 reads/thread, 1.4e7 conflict cyc.

constexpr int H = 512, W = 512, F = 8;
constexpr int IMAGES = 12;               // B*T
constexpr int TILE_W = 128;              // output pixels per block
constexpr int SEG_H  = 16;               // output rows per block
constexpr int SUN    = (TILE_W + 2) * 2; // 260 staged (px,q) units
constexpr int STRIPS = W / TILE_W;       // 4
constexpr int SEGS   = H / SEG_H;        // 32
constexpr size_t IMG_ELEMS = (size_t)H * W * F;

__device__ __forceinline__ void lgkm_barrier() {
    // __syncthreads() drains vmcnt too, which would kill the cross-iteration
    // global prefetch. LDS correctness only needs lgkmcnt(0) + s_barrier.
    asm volatile("s_waitcnt lgkmcnt(0)\n\ts_barrier" ::: "memory");
}

__device__ __forceinline__ float4 sub4(float4 a, float4 b) {
    return make_float4(a.x - b.x, a.y - b.y, a.z - b.z, a.w - b.w);
}

__device__ __forceinline__ unsigned packm(int4 m, bool in) {
    unsigned pk = (unsigned)(m.x | (m.y << 1) | (m.z << 2) | (m.w << 3));
    return in ? pk : 0u;
}

__device__ __forceinline__ void load_raw(const float* __restrict__ pred,
                                         const float* __restrict__ tgt,
                                         const int*   __restrict__ mask,
                                         size_t ibase, int h, int gp, int q,
                                         float4& p, float4& t, int4& m, bool& in)
{
    in = (h >= 0) & (h < H) & (gp >= 0) & (gp < W);
    const int hc  = min(max(h, 0), H - 1);
    const int gpc = min(max(gp, 0), W - 1);
    const size_t off = ibase + ((size_t)hc * W + gpc) * F + q * 4;
    p = *(const float4*)(pred + off);
    t = *(const float4*)(tgt + off);
    m = *(const int4*)(mask + off);
}

__global__ __launch_bounds__(256) void sobel_loss_kernel(
    const float* __restrict__ pred,
    const float* __restrict__ tgt,
    const int*   __restrict__ mask,
    float*       __restrict__ out)
{
    __shared__ float4   sv1[2][SUN];   // 8320 B
    __shared__ float4   sv2[2][SUN];   // 8320 B
    __shared__ unsigned smv[2][SUN];   // 2080 B

    const int tid = threadIdx.x;
    const int q   = tid & 1;
    const int pl  = tid >> 1;                 // 0..127 staged pixel
    const int bid = blockIdx.x;
    const int img   = bid >> 7;               // / (STRIPS*SEGS)
    const int r     = bid & 127;
    const int strip = r >> 5;                 // / SEGS
    const int seg   = r & 31;
    const int w0 = strip * TILE_W;
    const int h0 = seg * SEG_H;
    const size_t ibase = (size_t)img * IMG_ELEMS;
    const int gp = w0 - 1 + pl;               // staged global pixel (left halo)

    // Warmup: rows h0-1, h0, h0+1 into the register ring.
    float4 dm1, d0c, dp1;
    unsigned mm1, m0c, mp1;
    {
        float4 p, t; int4 m; bool in;
        load_raw(pred, tgt, mask, ibase, h0 - 1, gp, q, p, t, m, in);
        dm1 = sub4(p, t); mm1 = packm(m, in);
        load_raw(pred, tgt, mask, ibase, h0,     gp, q, p, t, m, in);
        d0c = sub4(p, t); m0c = packm(m, in);
        load_raw(pred, tgt, mask, ibase, h0 + 1, gp, q, p, t, m, in);
        dp1 = sub4(p, t); mp1 = packm(m, in);
    }

    for (int h = h0; h < h0 + SEG_H; ++h) {
        // Prefetch row h+2 raw (subtract/pack deferred to rotate so the
        // compiler doesn't stall on the load here).
        float4 pn, tn; int4 mn4; bool inn;
        load_raw(pred, tgt, mask, ibase, h + 2, gp, q, pn, tn, mn4, inn);

        const int s = h & 1;

        // Right-halo units (staged px 128,129): lanes 0..3, loaded in-step.
        if (tid < 4) {
            const int hq  = tid & 1;
            const int hgp = w0 + 127 + (tid >> 1);
            float4 pa, ta, pb, tb, pc, tc; int4 ma4, mb4, mc4; bool ia, ib, ic;
            load_raw(pred, tgt, mask, ibase, h - 1, hgp, hq, pa, ta, ma4, ia);
            load_raw(pred, tgt, mask, ibase, h,     hgp, hq, pb, tb, mb4, ib);
            load_raw(pred, tgt, mask, ibase, h + 1, hgp, hq, pc, tc, mc4, ic);
            const float4 a = sub4(pa, ta), b = sub4(pb, tb), c = sub4(pc, tc);
            sv1[s][256 + tid] = make_float4(a.x + 2.f * b.x + c.x,
                                            a.y + 2.f * b.y + c.y,
                                            a.z + 2.f * b.z + c.z,
                                            a.w + 2.f * b.w + c.w);
            sv2[s][256 + tid] = sub4(c, a);
            smv[s][256 + tid] = packm(ma4, ia) & packm(mb4, ib) & packm(mc4, ic);
        }

        // Vertical pass for own column (registers only).
        const float4 v1 = make_float4(dm1.x + 2.f * d0c.x + dp1.x,
                                      dm1.y + 2.f * d0c.y + dp1.y,
                                      dm1.z + 2.f * d0c.z + dp1.z,
                                      dm1.w + 2.f * d0c.w + dp1.w);
        const float4 v2 = sub4(dp1, dm1);
        const unsigned mv = mm1 & m0c & mp1;
        sv1[s][tid] = v1;
        sv2[s][tid] = v2;
        smv[s][tid] = mv;

        lgkm_barrier();

        // Horizontal pass: left neighbor = own registers.
        const float4 v1r = sv1[s][tid + 4];
        const float4 v2m = sv2[s][tid + 2];
        const float4 v2r = sv2[s][tid + 4];
        const unsigned valid = mv & smv[s][tid + 2] & smv[s][tid + 4];

        float4 res;
        res.x = (valid & 1u) ? fabsf(v1r.x - v1.x) + fabsf(v2.x + 2.f * v2m.x + v2r.x) : 0.f;
        res.y = (valid & 2u) ? fabsf(v1r.y - v1.y) + fabsf(v2.y + 2.f * v2m.y + v2r.y) : 0.f;
        res.z = (valid & 4u) ? fabsf(v1r.z - v1.z) + fabsf(v2.z + 2.f * v2m.z + v2r.z) : 0.f;
        res.w = (valid & 8u) ? fabsf(v1r.w - v1.w) + fabsf(v2.w + 2.f * v2m.w + v2r.w) : 0.f;

        *(float4*)(out + ibase + ((size_t)h * W + (w0 + pl)) * F + q * 4) = res;

        // Rotate ring; fold in the prefetched row.
        dm1 = d0c; mm1 = m0c;
        d0c = dp1; m0c = mp1;
        dp1 = sub4(pn, tn); mp1 = packm(mn4, inn);
    }
}

extern "C" void kernel_launch(void* const* d_in, const int* in_sizes, int n_in,
                              void* d_out, int out_size, void* d_ws, size_t ws_size,
                              hipStream_t stream) {
    const float* pred = (const float*)d_in[0];
    const float* tgt  = (const float*)d_in[1];
    const int*   mask = (const int*)d_in[2];
    float*       out  = (float*)d_out;

    const int blocks = IMAGES * STRIPS * SEGS;   // 12*4*32 = 1536
    sobel_loss_kernel<<<blocks, 256, 0, stream>>>(pred, tgt, mask, out);
}